// Round 2
// baseline (661.889 us; speedup 1.0000x reference)
//
#include <hip/hip_runtime.h>
#include <hip/hip_bf16.h>
#include <math.h>

#define N_NODES 50000
#define F_IN 128
#define HC 128
#define N_EDGES 800000
#define E_TOT (N_EDGES + N_NODES)   // 850000
#define NEG_SLOPE 0.2f
#define GN_EPS 1e-5f

// ---------------------------------------------------------------- init
__global__ __launch_bounds__(256) void init_k(int* __restrict__ deg,
                                              float* __restrict__ gsum,
                                              float* __restrict__ gsumsq) {
    int i = blockIdx.x * 256 + threadIdx.x;
    if (i < N_NODES) deg[i] = 0;
    if (i < HC) { gsum[i] = 0.f; gsumsq[i] = 0.f; }
}

// ---------------------------------------------------------------- fused dual GEMM (fp32 vector)
// x [N,128] @ {W_l, W_r} -> xl, xr in ONE pass (A-tile staged once).
// 256 threads, tile 64 rows x 128 cols, K chunked by 32. LDS = 46 KB -> 3 blocks/CU.
__global__ __launch_bounds__(256) void gemm_k(const float* __restrict__ x,
                                              const float* __restrict__ Wl,
                                              const float* __restrict__ Wr,
                                              float* __restrict__ xl,
                                              float* __restrict__ xr) {
    __shared__ float As[64][36];
    __shared__ float Bl[128][36];
    __shared__ float Br[128][36];
    const int tid = threadIdx.x;
    const int row0 = blockIdx.x * 64;
    float accL[8][4], accR[8][4];
#pragma unroll
    for (int r = 0; r < 8; ++r)
#pragma unroll
        for (int c = 0; c < 4; ++c) { accL[r][c] = 0.f; accR[r][c] = 0.f; }
    const int tcol = tid & 31;      // cols 4*tcol .. +3
    const int trow = tid >> 5;      // rows trow + 8*r

    for (int k0 = 0; k0 < 128; k0 += 32) {
        // stage A: 64 rows x 32 k (each thread: 8 floats)
        {
            int arow = tid >> 2, aseg = (tid & 3) * 8;
            int grow = row0 + arow;
            const float* ap = x + (size_t)(grow < N_NODES ? grow : (N_NODES - 1)) * F_IN + k0 + aseg;
            float4 v0 = *(const float4*)(ap + 0);
            float4 v1 = *(const float4*)(ap + 4);
            *(float4*)&As[arow][aseg + 0] = v0;
            *(float4*)&As[arow][aseg + 4] = v1;
        }
        // stage both B tiles transposed: Bs[col][k]
        {
            int kr4 = (tid >> 5) * 4, col4 = (tid & 31) * 4;
#pragma unroll
            for (int i = 0; i < 4; ++i) {
                int k = k0 + kr4 + i;
                float4 wl = *(const float4*)(Wl + (size_t)k * HC + col4);
                float4 wr = *(const float4*)(Wr + (size_t)k * HC + col4);
                Bl[col4 + 0][kr4 + i] = wl.x;
                Bl[col4 + 1][kr4 + i] = wl.y;
                Bl[col4 + 2][kr4 + i] = wl.z;
                Bl[col4 + 3][kr4 + i] = wl.w;
                Br[col4 + 0][kr4 + i] = wr.x;
                Br[col4 + 1][kr4 + i] = wr.y;
                Br[col4 + 2][kr4 + i] = wr.z;
                Br[col4 + 3][kr4 + i] = wr.w;
            }
        }
        __syncthreads();
#pragma unroll
        for (int k = 0; k < 32; k += 4) {
            float4 bl0 = *(float4*)&Bl[tcol * 4 + 0][k];
            float4 bl1 = *(float4*)&Bl[tcol * 4 + 1][k];
            float4 bl2 = *(float4*)&Bl[tcol * 4 + 2][k];
            float4 bl3 = *(float4*)&Bl[tcol * 4 + 3][k];
            float4 br0 = *(float4*)&Br[tcol * 4 + 0][k];
            float4 br1 = *(float4*)&Br[tcol * 4 + 1][k];
            float4 br2 = *(float4*)&Br[tcol * 4 + 2][k];
            float4 br3 = *(float4*)&Br[tcol * 4 + 3][k];
#pragma unroll
            for (int r = 0; r < 8; ++r) {
                float4 a = *(float4*)&As[trow + 8 * r][k];
                accL[r][0] += a.x * bl0.x + a.y * bl0.y + a.z * bl0.z + a.w * bl0.w;
                accL[r][1] += a.x * bl1.x + a.y * bl1.y + a.z * bl1.z + a.w * bl1.w;
                accL[r][2] += a.x * bl2.x + a.y * bl2.y + a.z * bl2.z + a.w * bl2.w;
                accL[r][3] += a.x * bl3.x + a.y * bl3.y + a.z * bl3.z + a.w * bl3.w;
                accR[r][0] += a.x * br0.x + a.y * br0.y + a.z * br0.z + a.w * br0.w;
                accR[r][1] += a.x * br1.x + a.y * br1.y + a.z * br1.z + a.w * br1.w;
                accR[r][2] += a.x * br2.x + a.y * br2.y + a.z * br2.z + a.w * br2.w;
                accR[r][3] += a.x * br3.x + a.y * br3.y + a.z * br3.z + a.w * br3.w;
            }
        }
        __syncthreads();
    }
#pragma unroll
    for (int r = 0; r < 8; ++r) {
        int grow = row0 + trow + 8 * r;
        if (grow < N_NODES) {
            *(float4*)(xl + (size_t)grow * HC + tcol * 4) =
                make_float4(accL[r][0], accL[r][1], accL[r][2], accL[r][3]);
            *(float4*)(xr + (size_t)grow * HC + tcol * 4) =
                make_float4(accR[r][0], accR[r][1], accR[r][2], accR[r][3]);
        }
    }
}

// ---------------------------------------------------------------- degree histogram
__global__ __launch_bounds__(256) void hist_k(const int* __restrict__ ei,
                                              int* __restrict__ deg) {
    int e = blockIdx.x * 256 + threadIdx.x;
    if (e >= E_TOT) return;
    int dst = (e < N_EDGES) ? ei[N_EDGES + e] : (e - N_EDGES);
    atomicAdd(&deg[dst], 1);
}

// ---------------------------------------------------------------- exclusive scan (1 block)
__global__ __launch_bounds__(1024) void scan_k(const int* __restrict__ deg,
                                               int* __restrict__ rowptr,
                                               int* __restrict__ cursor) {
    const int CHUNK = 49;   // 1024*49 = 50176 >= 50000
    int tid = threadIdx.x, lane = tid & 63, wid = tid >> 6;
    int base = tid * CHUNK;
    int local[CHUNK];
    int sum = 0;
#pragma unroll
    for (int j = 0; j < CHUNK; ++j) {
        int i = base + j;
        int v = (i < N_NODES) ? deg[i] : 0;
        local[j] = sum;
        sum += v;
    }
    int incl = sum;
#pragma unroll
    for (int d = 1; d < 64; d <<= 1) {
        int t = __shfl_up(incl, d, 64);
        if (lane >= d) incl += t;
    }
    __shared__ int wtot[16];
    __shared__ int woff[16];
    if (lane == 63) wtot[wid] = incl;
    __syncthreads();
    if (tid == 0) {
        int run = 0;
#pragma unroll
        for (int w = 0; w < 16; ++w) { woff[w] = run; run += wtot[w]; }
    }
    __syncthreads();
    int excl = woff[wid] + incl - sum;
#pragma unroll
    for (int j = 0; j < CHUNK; ++j) {
        int i = base + j;
        if (i < N_NODES) {
            int val = excl + local[j];
            rowptr[i] = val;
            cursor[i] = val;
        }
    }
    if (tid == 1023) rowptr[N_NODES] = excl + sum;   // total = E_TOT
}

// ---------------------------------------------------------------- CSR fill
__global__ __launch_bounds__(256) void fill_k(const int* __restrict__ ei,
                                              int* __restrict__ cursor,
                                              int* __restrict__ csr) {
    int e = blockIdx.x * 256 + threadIdx.x;
    if (e >= E_TOT) return;
    int src, dst;
    if (e < N_EDGES) { src = ei[e]; dst = ei[N_EDGES + e]; }
    else             { src = dst = e - N_EDGES; }
    int pos = atomicAdd(&cursor[dst], 1);
    csr[pos] = src;
}

// ---------------------------------------------------------------- fused attention
// One wave per dst. Scores are tiny (|score| < ~3) so softmax needs no max
// subtraction (shift-invariant) -> plain sum of exp, no serial rescale chain.
// Lane layout: pair = lane>>5 selects edge A/B, s = lane&31 owns channels
// 4s..4s+3 (float4). Two edges per wave-step, 4 gathers in flight (unroll 2).
__global__ __launch_bounds__(256) void attn_k(const float* __restrict__ xl,
                                              const float* __restrict__ xr,
                                              const int* __restrict__ rowptr,
                                              const int* __restrict__ csr,
                                              const float* __restrict__ att,
                                              const float* __restrict__ bias,
                                              float* __restrict__ out) {
    const int wid = threadIdx.x >> 6, lane = threadIdx.x & 63;
    const int dst = blockIdx.x * 4 + wid;
    if (dst >= N_NODES) return;
    const int pair = lane >> 5, s = lane & 31;
    const float4 xrv = *(const float4*)(xr + (size_t)dst * HC + s * 4);
    const float4 av  = *(const float4*)(att + s * 4);
    float l = 0.f;
    float4 acc = make_float4(0.f, 0.f, 0.f, 0.f);
    const int start = rowptr[dst], end = rowptr[dst + 1];

    for (int kb = start; kb < end; kb += 64) {
        int nk = min(64, end - kb);
        int sv = (kb + lane < end) ? csr[kb + lane] : 0;
        int j = 0;
        for (; j + 4 <= nk; j += 4) {
            int srcA = __shfl(sv, j + pair, 64);
            int srcB = __shfl(sv, j + 2 + pair, 64);
            float4 xa = *(const float4*)(xl + (size_t)srcA * HC + s * 4);
            float4 xb = *(const float4*)(xl + (size_t)srcB * HC + s * 4);
            {
                float t0 = xa.x + xrv.x; t0 = t0 > 0.f ? t0 : NEG_SLOPE * t0;
                float t1 = xa.y + xrv.y; t1 = t1 > 0.f ? t1 : NEG_SLOPE * t1;
                float t2 = xa.z + xrv.z; t2 = t2 > 0.f ? t2 : NEG_SLOPE * t2;
                float t3 = xa.w + xrv.w; t3 = t3 > 0.f ? t3 : NEG_SLOPE * t3;
                float part = av.x * t0 + av.y * t1 + av.z * t2 + av.w * t3;
                part += __shfl_xor(part, 1, 8);
                part += __shfl_xor(part, 2, 8);
                part += __shfl_xor(part, 4, 8);
                float p = __expf(part);
                l += p;
                acc.x += p * xa.x; acc.y += p * xa.y;
                acc.z += p * xa.z; acc.w += p * xa.w;
            }
            {
                float t0 = xb.x + xrv.x; t0 = t0 > 0.f ? t0 : NEG_SLOPE * t0;
                float t1 = xb.y + xrv.y; t1 = t1 > 0.f ? t1 : NEG_SLOPE * t1;
                float t2 = xb.z + xrv.z; t2 = t2 > 0.f ? t2 : NEG_SLOPE * t2;
                float t3 = xb.w + xrv.w; t3 = t3 > 0.f ? t3 : NEG_SLOPE * t3;
                float part = av.x * t0 + av.y * t1 + av.z * t2 + av.w * t3;
                part += __shfl_xor(part, 1, 8);
                part += __shfl_xor(part, 2, 8);
                part += __shfl_xor(part, 4, 8);
                float p = __expf(part);
                l += p;
                acc.x += p * xb.x; acc.y += p * xb.y;
                acc.z += p * xb.z; acc.w += p * xb.w;
            }
        }
        for (; j < nk; j += 2) {
            int idx = j + pair;
            bool valid = idx < nk;
            int src = __shfl(sv, valid ? idx : 0, 64);
            float4 xa = *(const float4*)(xl + (size_t)src * HC + s * 4);
            float t0 = xa.x + xrv.x; t0 = t0 > 0.f ? t0 : NEG_SLOPE * t0;
            float t1 = xa.y + xrv.y; t1 = t1 > 0.f ? t1 : NEG_SLOPE * t1;
            float t2 = xa.z + xrv.z; t2 = t2 > 0.f ? t2 : NEG_SLOPE * t2;
            float t3 = xa.w + xrv.w; t3 = t3 > 0.f ? t3 : NEG_SLOPE * t3;
            float part = av.x * t0 + av.y * t1 + av.z * t2 + av.w * t3;
            part += __shfl_xor(part, 1, 8);
            part += __shfl_xor(part, 2, 8);
            part += __shfl_xor(part, 4, 8);
            float p = valid ? __expf(part) : 0.f;
            l += p;
            acc.x += p * xa.x; acc.y += p * xa.y;
            acc.z += p * xa.z; acc.w += p * xa.w;
        }
    }
    // combine the two edge-halves
    l     += __shfl_xor(l, 32, 64);
    acc.x += __shfl_xor(acc.x, 32, 64);
    acc.y += __shfl_xor(acc.y, 32, 64);
    acc.z += __shfl_xor(acc.z, 32, 64);
    acc.w += __shfl_xor(acc.w, 32, 64);
    if (pair == 0) {
        float inv = 1.0f / l;
        float4 bv = *(const float4*)(bias + s * 4);
        float4 o = make_float4(acc.x * inv + bv.x, acc.y * inv + bv.y,
                               acc.z * inv + bv.z, acc.w * inv + bv.w);
        *(float4*)(out + (size_t)dst * HC + s * 4) = o;
    }
}

// ---------------------------------------------------------------- per-feature sum/sumsq
__global__ __launch_bounds__(256) void stats_k(const float* __restrict__ out,
                                               float* __restrict__ gsum,
                                               float* __restrict__ gsumsq) {
    int f = threadIdx.x & 127;
    int half = threadIdx.x >> 7;
    float s = 0.f, s2 = 0.f;
    for (int r = blockIdx.x * 2 + half; r < N_NODES; r += gridDim.x * 2) {
        float v = out[(size_t)r * HC + f];
        s += v; s2 += v * v;
    }
    __shared__ float l1[256], l2[256];
    l1[threadIdx.x] = s; l2[threadIdx.x] = s2;
    __syncthreads();
    if (threadIdx.x < 128) {
        s  = l1[threadIdx.x] + l1[threadIdx.x + 128];
        s2 = l2[threadIdx.x] + l2[threadIdx.x + 128];
        atomicAdd(&gsum[f], s);
        atomicAdd(&gsumsq[f], s2);
    }
}

// ---------------------------------------------------------------- GraphNorm finalize (in place on d_out)
__global__ __launch_bounds__(256) void norm_k(float* __restrict__ out,
                                              const float* __restrict__ gsum,
                                              const float* __restrict__ gsumsq,
                                              const float* __restrict__ gw,
                                              const float* __restrict__ gb,
                                              const float* __restrict__ gms) {
    int f = threadIdx.x & 127;
    int half = threadIdx.x >> 7;
    const float invN = 1.0f / (float)N_NODES;
    float mean = gsum[f] * invN;
    float msq  = gsumsq[f] * invN;
    float g = gms[f];
    float var = msq - 2.f * g * mean * mean + g * g * mean * mean;
    float rstd = rsqrtf(var + GN_EPS);
    float a = gw[f] * rstd;
    float b = gb[f] - a * g * mean;
    for (int r = blockIdx.x * 2 + half; r < N_NODES; r += gridDim.x * 2) {
        size_t o = (size_t)r * HC + f;
        out[o] = a * out[o] + b;
    }
}

// ---------------------------------------------------------------- launch
extern "C" void kernel_launch(void* const* d_in, const int* in_sizes, int n_in,
                              void* d_out, int out_size, void* d_ws, size_t ws_size,
                              hipStream_t stream) {
    const float* x    = (const float*)d_in[0];
    const int*   ei   = (const int*)d_in[1];
    const float* Wl   = (const float*)d_in[2];
    const float* Wr   = (const float*)d_in[3];
    const float* att  = (const float*)d_in[4];
    const float* bias = (const float*)d_in[5];
    const float* gw   = (const float*)d_in[6];
    const float* gb   = (const float*)d_in[7];
    const float* gms  = (const float*)d_in[8];
    float* out = (float*)d_out;

    float* xl     = (float*)d_ws;
    float* xr     = xl + (size_t)N_NODES * HC;
    float* gsum   = xr + (size_t)N_NODES * HC;
    float* gsumsq = gsum + HC;
    int*   deg    = (int*)(gsumsq + HC);
    int*   rowptr = deg + N_NODES;
    int*   cursor = rowptr + (N_NODES + 1);
    int*   csr    = cursor + N_NODES;

    hipLaunchKernelGGL(init_k, dim3((N_NODES + 255) / 256), dim3(256), 0, stream,
                       deg, gsum, gsumsq);
    hipLaunchKernelGGL(gemm_k, dim3((N_NODES + 63) / 64), dim3(256), 0, stream,
                       x, Wl, Wr, xl, xr);
    hipLaunchKernelGGL(hist_k, dim3((E_TOT + 255) / 256), dim3(256), 0, stream,
                       ei, deg);
    hipLaunchKernelGGL(scan_k, dim3(1), dim3(1024), 0, stream,
                       deg, rowptr, cursor);
    hipLaunchKernelGGL(fill_k, dim3((E_TOT + 255) / 256), dim3(256), 0, stream,
                       ei, cursor, csr);
    hipLaunchKernelGGL(attn_k, dim3((N_NODES + 3) / 4), dim3(256), 0, stream,
                       xl, xr, rowptr, csr, att, bias, out);
    hipLaunchKernelGGL(stats_k, dim3(256), dim3(256), 0, stream,
                       out, gsum, gsumsq);
    hipLaunchKernelGGL(norm_k, dim3(512), dim3(256), 0, stream,
                       out, gsum, gsumsq, gw, gb, gms);
}

// Round 3
// 376.255 us; speedup vs baseline: 1.7592x; 1.7592x over previous
//
#include <hip/hip_runtime.h>
#include <hip/hip_bf16.h>
#include <math.h>

#define N_NODES 50000
#define F_IN 128
#define HC 128
#define N_EDGES 800000
#define E_TOT (N_EDGES + N_NODES)   // 850000
#define NEG_SLOPE 0.2f
#define GN_EPS 1e-5f

typedef __attribute__((ext_vector_type(8))) short short8;
typedef __attribute__((ext_vector_type(4))) float floatx4;

__device__ inline ushort f2bf(float f) {
    unsigned u = __float_as_uint(f);
    u += 0x7FFF + ((u >> 16) & 1);   // RNE (inputs are finite/bounded)
    return (ushort)(u >> 16);
}

// ---------------------------------------------------------------- init (+ W cast/transpose to bf16)
// wt_g layout: [n][k] (transposed), n-major, 128x128 bf16 per matrix.
__global__ __launch_bounds__(256) void init_k(int* __restrict__ deg,
                                              float* __restrict__ gsum,
                                              float* __restrict__ gsumsq,
                                              const float* __restrict__ Wl,
                                              const float* __restrict__ Wr,
                                              ushort* __restrict__ wtl,
                                              ushort* __restrict__ wtr) {
    int i = blockIdx.x * 256 + threadIdx.x;
    if (i < N_NODES) deg[i] = 0;
    if (i < HC) { gsum[i] = 0.f; gsumsq[i] = 0.f; }
    if (i < 16384) {                 // W is [k][n] row-major; write [n][k]
        int k = i >> 7, n = i & 127;
        wtl[n * 128 + k] = f2bf(Wl[i]);
        wtr[n * 128 + k] = f2bf(Wr[i]);
    }
}

// ---------------------------------------------------------------- MFMA GEMM (bf16 in, fp32 out)
// x [N,128] fp32 @ W[128,128] -> out [N,128] fp32. grid=(782, 2): y=0 -> xl (wtl), y=1 -> xr (wtr).
// Block: 256 thr = 4 waves, 64 rows; wave w owns rows row0+16w..+15.
// MFMA 16x16x32 bf16: A[m=lane&15][k=quad*8+j]; B[k=quad*8+j][n=lane&15];
// C/D: row=quad*4+reg, col=lane&15 (m89/m91-verified).
__global__ __launch_bounds__(256) void gemm_k(const float* __restrict__ x,
                                              const ushort* __restrict__ wtl,
                                              const ushort* __restrict__ wtr,
                                              float* __restrict__ xl,
                                              float* __restrict__ xr) {
    const ushort* Wg = blockIdx.y ? wtr : wtl;
    float* out = blockIdx.y ? xr : xl;
    __shared__ ushort Wt[128][136];      // row stride 272 B (16B-aligned)
    const int tid = threadIdx.x;
    // stage Wt: 8 iters x 256 thr x 16 B = 32 KB, coalesced global, b128 LDS writes
#pragma unroll
    for (int i = 0; i < 8; ++i) {
        int n = i * 16 + (tid >> 4);
        int k8 = (tid & 15) * 8;
        *(int4*)&Wt[n][k8] = *(const int4*)(Wg + n * 128 + k8);
    }
    __syncthreads();

    const int w = tid >> 6, lane = tid & 63;
    const int quad = lane >> 4, l16 = lane & 15;
    const int rbase = blockIdx.x * 64 + w * 16;
    const int grow = rbase + l16;
    const float* ap = x + (size_t)(grow < N_NODES ? grow : (N_NODES - 1)) * F_IN + quad * 8;

    floatx4 acc[8];
#pragma unroll
    for (int nt = 0; nt < 8; ++nt) acc[nt] = (floatx4){0.f, 0.f, 0.f, 0.f};

#pragma unroll
    for (int ks = 0; ks < 4; ++ks) {
        float4 a0 = *(const float4*)(ap + ks * 32 + 0);
        float4 a1 = *(const float4*)(ap + ks * 32 + 4);
        short8 af;
        af[0] = (short)f2bf(a0.x); af[1] = (short)f2bf(a0.y);
        af[2] = (short)f2bf(a0.z); af[3] = (short)f2bf(a0.w);
        af[4] = (short)f2bf(a1.x); af[5] = (short)f2bf(a1.y);
        af[6] = (short)f2bf(a1.z); af[7] = (short)f2bf(a1.w);
#pragma unroll
        for (int nt = 0; nt < 8; ++nt) {
            short8 bf = *(const short8*)&Wt[nt * 16 + l16][ks * 32 + quad * 8];
            acc[nt] = __builtin_amdgcn_mfma_f32_16x16x32_bf16(af, bf, acc[nt], 0, 0, 0);
        }
    }
    // epilogue: row = rbase + quad*4 + r, col = nt*16 + l16
#pragma unroll
    for (int r = 0; r < 4; ++r) {
        int gro = rbase + quad * 4 + r;
        if (gro < N_NODES) {
            float* op = out + (size_t)gro * HC + l16;
#pragma unroll
            for (int nt = 0; nt < 8; ++nt) op[nt * 16] = acc[nt][r];
        }
    }
}

// ---------------------------------------------------------------- degree histogram
__global__ __launch_bounds__(256) void hist_k(const int* __restrict__ ei,
                                              int* __restrict__ deg) {
    int e = blockIdx.x * 256 + threadIdx.x;
    if (e >= E_TOT) return;
    int dst = (e < N_EDGES) ? ei[N_EDGES + e] : (e - N_EDGES);
    atomicAdd(&deg[dst], 1);
}

// ---------------------------------------------------------------- exclusive scan (1 block)
__global__ __launch_bounds__(1024) void scan_k(const int* __restrict__ deg,
                                               int* __restrict__ rowptr,
                                               int* __restrict__ cursor) {
    const int CHUNK = 49;   // 1024*49 = 50176 >= 50000
    int tid = threadIdx.x, lane = tid & 63, wid = tid >> 6;
    int base = tid * CHUNK;
    int local[CHUNK];
    int sum = 0;
#pragma unroll
    for (int j = 0; j < CHUNK; ++j) {
        int i = base + j;
        int v = (i < N_NODES) ? deg[i] : 0;
        local[j] = sum;
        sum += v;
    }
    int incl = sum;
#pragma unroll
    for (int d = 1; d < 64; d <<= 1) {
        int t = __shfl_up(incl, d, 64);
        if (lane >= d) incl += t;
    }
    __shared__ int wtot[16];
    __shared__ int woff[16];
    if (lane == 63) wtot[wid] = incl;
    __syncthreads();
    if (tid == 0) {
        int run = 0;
#pragma unroll
        for (int w = 0; w < 16; ++w) { woff[w] = run; run += wtot[w]; }
    }
    __syncthreads();
    int excl = woff[wid] + incl - sum;
#pragma unroll
    for (int j = 0; j < CHUNK; ++j) {
        int i = base + j;
        if (i < N_NODES) {
            int val = excl + local[j];
            rowptr[i] = val;
            cursor[i] = val;
        }
    }
    if (tid == 1023) rowptr[N_NODES] = excl + sum;   // total = E_TOT
}

// ---------------------------------------------------------------- CSR fill
__global__ __launch_bounds__(256) void fill_k(const int* __restrict__ ei,
                                              int* __restrict__ cursor,
                                              int* __restrict__ csr) {
    int e = blockIdx.x * 256 + threadIdx.x;
    if (e >= E_TOT) return;
    int src, dst;
    if (e < N_EDGES) { src = ei[e]; dst = ei[N_EDGES + e]; }
    else             { src = dst = e - N_EDGES; }
    int pos = atomicAdd(&cursor[dst], 1);
    csr[pos] = src;
}

// ---------------------------------------------------------------- fused attention
// One wave per dst; plain-sum softmax (scores bounded, shift-invariant).
// pair = lane>>5 selects edge A/B; s = lane&31 owns channels 4s..4s+3.
__global__ __launch_bounds__(256) void attn_k(const float* __restrict__ xl,
                                              const float* __restrict__ xr,
                                              const int* __restrict__ rowptr,
                                              const int* __restrict__ csr,
                                              const float* __restrict__ att,
                                              const float* __restrict__ bias,
                                              float* __restrict__ out) {
    const int wid = threadIdx.x >> 6, lane = threadIdx.x & 63;
    const int dst = blockIdx.x * 4 + wid;
    if (dst >= N_NODES) return;
    const int pair = lane >> 5, s = lane & 31;
    const float4 xrv = *(const float4*)(xr + (size_t)dst * HC + s * 4);
    const float4 av  = *(const float4*)(att + s * 4);
    float l = 0.f;
    float4 acc = make_float4(0.f, 0.f, 0.f, 0.f);
    const int start = rowptr[dst], end = rowptr[dst + 1];

    for (int kb = start; kb < end; kb += 64) {
        int nk = min(64, end - kb);
        int sv = (kb + lane < end) ? csr[kb + lane] : 0;
        int j = 0;
        for (; j + 4 <= nk; j += 4) {
            int srcA = __shfl(sv, j + pair, 64);
            int srcB = __shfl(sv, j + 2 + pair, 64);
            float4 xa = *(const float4*)(xl + (size_t)srcA * HC + s * 4);
            float4 xb = *(const float4*)(xl + (size_t)srcB * HC + s * 4);
            {
                float t0 = xa.x + xrv.x; t0 = t0 > 0.f ? t0 : NEG_SLOPE * t0;
                float t1 = xa.y + xrv.y; t1 = t1 > 0.f ? t1 : NEG_SLOPE * t1;
                float t2 = xa.z + xrv.z; t2 = t2 > 0.f ? t2 : NEG_SLOPE * t2;
                float t3 = xa.w + xrv.w; t3 = t3 > 0.f ? t3 : NEG_SLOPE * t3;
                float part = av.x * t0 + av.y * t1 + av.z * t2 + av.w * t3;
                part += __shfl_xor(part, 1, 8);
                part += __shfl_xor(part, 2, 8);
                part += __shfl_xor(part, 4, 8);
                float p = __expf(part);
                l += p;
                acc.x += p * xa.x; acc.y += p * xa.y;
                acc.z += p * xa.z; acc.w += p * xa.w;
            }
            {
                float t0 = xb.x + xrv.x; t0 = t0 > 0.f ? t0 : NEG_SLOPE * t0;
                float t1 = xb.y + xrv.y; t1 = t1 > 0.f ? t1 : NEG_SLOPE * t1;
                float t2 = xb.z + xrv.z; t2 = t2 > 0.f ? t2 : NEG_SLOPE * t2;
                float t3 = xb.w + xrv.w; t3 = t3 > 0.f ? t3 : NEG_SLOPE * t3;
                float part = av.x * t0 + av.y * t1 + av.z * t2 + av.w * t3;
                part += __shfl_xor(part, 1, 8);
                part += __shfl_xor(part, 2, 8);
                part += __shfl_xor(part, 4, 8);
                float p = __expf(part);
                l += p;
                acc.x += p * xb.x; acc.y += p * xb.y;
                acc.z += p * xb.z; acc.w += p * xb.w;
            }
        }
        for (; j < nk; j += 2) {
            int idx = j + pair;
            bool valid = idx < nk;
            int src = __shfl(sv, valid ? idx : 0, 64);
            float4 xa = *(const float4*)(xl + (size_t)src * HC + s * 4);
            float t0 = xa.x + xrv.x; t0 = t0 > 0.f ? t0 : NEG_SLOPE * t0;
            float t1 = xa.y + xrv.y; t1 = t1 > 0.f ? t1 : NEG_SLOPE * t1;
            float t2 = xa.z + xrv.z; t2 = t2 > 0.f ? t2 : NEG_SLOPE * t2;
            float t3 = xa.w + xrv.w; t3 = t3 > 0.f ? t3 : NEG_SLOPE * t3;
            float part = av.x * t0 + av.y * t1 + av.z * t2 + av.w * t3;
            part += __shfl_xor(part, 1, 8);
            part += __shfl_xor(part, 2, 8);
            part += __shfl_xor(part, 4, 8);
            float p = valid ? __expf(part) : 0.f;
            l += p;
            acc.x += p * xa.x; acc.y += p * xa.y;
            acc.z += p * xa.z; acc.w += p * xa.w;
        }
    }
    l     += __shfl_xor(l, 32, 64);
    acc.x += __shfl_xor(acc.x, 32, 64);
    acc.y += __shfl_xor(acc.y, 32, 64);
    acc.z += __shfl_xor(acc.z, 32, 64);
    acc.w += __shfl_xor(acc.w, 32, 64);
    if (pair == 0) {
        float inv = 1.0f / l;
        float4 bv = *(const float4*)(bias + s * 4);
        float4 o = make_float4(acc.x * inv + bv.x, acc.y * inv + bv.y,
                               acc.z * inv + bv.z, acc.w * inv + bv.w);
        *(float4*)(out + (size_t)dst * HC + s * 4) = o;
    }
}

// ---------------------------------------------------------------- per-feature sum/sumsq
__global__ __launch_bounds__(256) void stats_k(const float* __restrict__ out,
                                               float* __restrict__ gsum,
                                               float* __restrict__ gsumsq) {
    int f = threadIdx.x & 127;
    int half = threadIdx.x >> 7;
    float s = 0.f, s2 = 0.f;
    for (int r = blockIdx.x * 2 + half; r < N_NODES; r += gridDim.x * 2) {
        float v = out[(size_t)r * HC + f];
        s += v; s2 += v * v;
    }
    __shared__ float l1[256], l2[256];
    l1[threadIdx.x] = s; l2[threadIdx.x] = s2;
    __syncthreads();
    if (threadIdx.x < 128) {
        s  = l1[threadIdx.x] + l1[threadIdx.x + 128];
        s2 = l2[threadIdx.x] + l2[threadIdx.x + 128];
        atomicAdd(&gsum[f], s);
        atomicAdd(&gsumsq[f], s2);
    }
}

// ---------------------------------------------------------------- GraphNorm finalize (in place on d_out)
__global__ __launch_bounds__(256) void norm_k(float* __restrict__ out,
                                              const float* __restrict__ gsum,
                                              const float* __restrict__ gsumsq,
                                              const float* __restrict__ gw,
                                              const float* __restrict__ gb,
                                              const float* __restrict__ gms) {
    int f = threadIdx.x & 127;
    int half = threadIdx.x >> 7;
    const float invN = 1.0f / (float)N_NODES;
    float mean = gsum[f] * invN;
    float msq  = gsumsq[f] * invN;
    float g = gms[f];
    float var = msq - 2.f * g * mean * mean + g * g * mean * mean;
    float rstd = rsqrtf(var + GN_EPS);
    float a = gw[f] * rstd;
    float b = gb[f] - a * g * mean;
    for (int r = blockIdx.x * 2 + half; r < N_NODES; r += gridDim.x * 2) {
        size_t o = (size_t)r * HC + f;
        out[o] = a * out[o] + b;
    }
}

// ---------------------------------------------------------------- launch
extern "C" void kernel_launch(void* const* d_in, const int* in_sizes, int n_in,
                              void* d_out, int out_size, void* d_ws, size_t ws_size,
                              hipStream_t stream) {
    const float* x    = (const float*)d_in[0];
    const int*   ei   = (const int*)d_in[1];
    const float* Wl   = (const float*)d_in[2];
    const float* Wr   = (const float*)d_in[3];
    const float* att  = (const float*)d_in[4];
    const float* bias = (const float*)d_in[5];
    const float* gw   = (const float*)d_in[6];
    const float* gb   = (const float*)d_in[7];
    const float* gms  = (const float*)d_in[8];
    float* out = (float*)d_out;

    float* xl     = (float*)d_ws;
    float* xr     = xl + (size_t)N_NODES * HC;
    float* gsum   = xr + (size_t)N_NODES * HC;
    float* gsumsq = gsum + HC;
    int*   deg    = (int*)(gsumsq + HC);
    int*   rowptr = deg + N_NODES;
    int*   cursor = rowptr + (N_NODES + 1);
    int*   csr    = cursor + N_NODES;
    ushort* wtl   = (ushort*)(csr + E_TOT);
    ushort* wtr   = wtl + 16384;

    hipLaunchKernelGGL(init_k, dim3((N_NODES + 255) / 256), dim3(256), 0, stream,
                       deg, gsum, gsumsq, Wl, Wr, wtl, wtr);
    hipLaunchKernelGGL(gemm_k, dim3((N_NODES + 63) / 64, 2), dim3(256), 0, stream,
                       x, wtl, wtr, xl, xr);
    hipLaunchKernelGGL(hist_k, dim3((E_TOT + 255) / 256), dim3(256), 0, stream,
                       ei, deg);
    hipLaunchKernelGGL(scan_k, dim3(1), dim3(1024), 0, stream,
                       deg, rowptr, cursor);
    hipLaunchKernelGGL(fill_k, dim3((E_TOT + 255) / 256), dim3(256), 0, stream,
                       ei, cursor, csr);
    hipLaunchKernelGGL(attn_k, dim3((N_NODES + 3) / 4), dim3(256), 0, stream,
                       xl, xr, rowptr, csr, att, bias, out);
    hipLaunchKernelGGL(stats_k, dim3(256), dim3(256), 0, stream,
                       out, gsum, gsumsq);
    hipLaunchKernelGGL(norm_k, dim3(512), dim3(256), 0, stream,
                       out, gsum, gsumsq, gw, gb, gms);
}

// Round 4
// 296.499 us; speedup vs baseline: 2.2323x; 1.2690x over previous
//
#include <hip/hip_runtime.h>
#include <hip/hip_bf16.h>
#include <math.h>

#define N_NODES 50000
#define F_IN 128
#define HC 128
#define N_EDGES 800000
#define E_TOT (N_EDGES + N_NODES)   // 850000
#define NEG_SLOPE 0.2f
#define GN_EPS 1e-5f
#define SCAN_B ((N_NODES + 255) / 256)   // 196 blocks

typedef __attribute__((ext_vector_type(8))) short short8;
typedef __attribute__((ext_vector_type(4))) float floatx4;

__device__ inline ushort f2bf(float f) {
    unsigned u = __float_as_uint(f);
    u += 0x7FFF + ((u >> 16) & 1);   // RNE (inputs are finite/bounded)
    return (ushort)(u >> 16);
}

// ---------------------------------------------------------------- init (+ W cast/transpose to bf16)
__global__ __launch_bounds__(256) void init_k(int* __restrict__ deg,
                                              float* __restrict__ gsum,
                                              float* __restrict__ gsumsq,
                                              const float* __restrict__ Wl,
                                              const float* __restrict__ Wr,
                                              ushort* __restrict__ wtl,
                                              ushort* __restrict__ wtr) {
    int i = blockIdx.x * 256 + threadIdx.x;
    if (i < N_NODES) deg[i] = 0;
    if (i < HC) { gsum[i] = 0.f; gsumsq[i] = 0.f; }
    if (i < 16384) {                 // W is [k][n] row-major; write [n][k]
        int k = i >> 7, n = i & 127;
        wtl[n * 128 + k] = f2bf(Wl[i]);
        wtr[n * 128 + k] = f2bf(Wr[i]);
    }
}

// ---------------------------------------------------------------- MFMA GEMM (bf16 in, fp32 out)
__global__ __launch_bounds__(256) void gemm_k(const float* __restrict__ x,
                                              const ushort* __restrict__ wtl,
                                              const ushort* __restrict__ wtr,
                                              float* __restrict__ xl,
                                              float* __restrict__ xr) {
    const ushort* Wg = blockIdx.y ? wtr : wtl;
    float* out = blockIdx.y ? xr : xl;
    __shared__ ushort Wt[128][136];      // row stride 272 B (16B-aligned)
    const int tid = threadIdx.x;
#pragma unroll
    for (int i = 0; i < 8; ++i) {
        int n = i * 16 + (tid >> 4);
        int k8 = (tid & 15) * 8;
        *(int4*)&Wt[n][k8] = *(const int4*)(Wg + n * 128 + k8);
    }
    __syncthreads();

    const int w = tid >> 6, lane = tid & 63;
    const int quad = lane >> 4, l16 = lane & 15;
    const int rbase = blockIdx.x * 64 + w * 16;
    const int grow = rbase + l16;
    const float* ap = x + (size_t)(grow < N_NODES ? grow : (N_NODES - 1)) * F_IN + quad * 8;

    floatx4 acc[8];
#pragma unroll
    for (int nt = 0; nt < 8; ++nt) acc[nt] = (floatx4){0.f, 0.f, 0.f, 0.f};

#pragma unroll
    for (int ks = 0; ks < 4; ++ks) {
        float4 a0 = *(const float4*)(ap + ks * 32 + 0);
        float4 a1 = *(const float4*)(ap + ks * 32 + 4);
        short8 af;
        af[0] = (short)f2bf(a0.x); af[1] = (short)f2bf(a0.y);
        af[2] = (short)f2bf(a0.z); af[3] = (short)f2bf(a0.w);
        af[4] = (short)f2bf(a1.x); af[5] = (short)f2bf(a1.y);
        af[6] = (short)f2bf(a1.z); af[7] = (short)f2bf(a1.w);
#pragma unroll
        for (int nt = 0; nt < 8; ++nt) {
            short8 bf = *(const short8*)&Wt[nt * 16 + l16][ks * 32 + quad * 8];
            acc[nt] = __builtin_amdgcn_mfma_f32_16x16x32_bf16(af, bf, acc[nt], 0, 0, 0);
        }
    }
#pragma unroll
    for (int r = 0; r < 4; ++r) {
        int gro = rbase + quad * 4 + r;
        if (gro < N_NODES) {
            float* op = out + (size_t)gro * HC + l16;
#pragma unroll
            for (int nt = 0; nt < 8; ++nt) op[nt * 16] = acc[nt][r];
        }
    }
}

// ---------------------------------------------------------------- degree histogram
__global__ __launch_bounds__(256) void hist_k(const int* __restrict__ ei,
                                              int* __restrict__ deg) {
    int e = blockIdx.x * 256 + threadIdx.x;
    if (e >= E_TOT) return;
    int dst = (e < N_EDGES) ? ei[N_EDGES + e] : (e - N_EDGES);
    atomicAdd(&deg[dst], 1);
}

// ---------------------------------------------------------------- scan phase 1: per-block local scan + block totals
__global__ __launch_bounds__(256) void scan1_k(const int* __restrict__ deg,
                                               int* __restrict__ rowptr,
                                               int* __restrict__ bsum) {
    int i = blockIdx.x * 256 + threadIdx.x;
    int v = (i < N_NODES) ? deg[i] : 0;
    int lane = threadIdx.x & 63, wid = threadIdx.x >> 6;
    int incl = v;
#pragma unroll
    for (int d = 1; d < 64; d <<= 1) {
        int t = __shfl_up(incl, d, 64);
        if (lane >= d) incl += t;
    }
    __shared__ int wt[4], wo[4];
    if (lane == 63) wt[wid] = incl;
    __syncthreads();
    if (threadIdx.x == 0) {
        int run = 0;
#pragma unroll
        for (int ww = 0; ww < 4; ++ww) { wo[ww] = run; run += wt[ww]; }
        bsum[blockIdx.x] = run;
    }
    __syncthreads();
    if (i < N_NODES) rowptr[i] = wo[wid] + incl - v;
}

// ---------------------------------------------------------------- scan phase 2: scan the 196 block totals
__global__ __launch_bounds__(256) void scan2_k(const int* __restrict__ bsum,
                                               int* __restrict__ boff) {
    int tid = threadIdx.x;
    int v = (tid < SCAN_B) ? bsum[tid] : 0;
    int lane = tid & 63, wid = tid >> 6;
    int incl = v;
#pragma unroll
    for (int d = 1; d < 64; d <<= 1) {
        int t = __shfl_up(incl, d, 64);
        if (lane >= d) incl += t;
    }
    __shared__ int wt[4], wo[4];
    if (lane == 63) wt[wid] = incl;
    __syncthreads();
    if (tid == 0) {
        int run = 0;
#pragma unroll
        for (int ww = 0; ww < 4; ++ww) { wo[ww] = run; run += wt[ww]; }
    }
    __syncthreads();
    if (tid < SCAN_B) boff[tid] = wo[wid] + incl - v;
}

// ---------------------------------------------------------------- scan phase 3: add offsets, mirror into cursor
__global__ __launch_bounds__(256) void scan3_k(int* __restrict__ rowptr,
                                               const int* __restrict__ boff,
                                               int* __restrict__ cursor) {
    int i = blockIdx.x * 256 + threadIdx.x;
    if (i < N_NODES) {
        int val = rowptr[i] + boff[blockIdx.x];
        rowptr[i] = val;
        cursor[i] = val;
    }
    if (i == 0) rowptr[N_NODES] = E_TOT;
}

// ---------------------------------------------------------------- CSR fill
__global__ __launch_bounds__(256) void fill_k(const int* __restrict__ ei,
                                              int* __restrict__ cursor,
                                              int* __restrict__ csr) {
    int e = blockIdx.x * 256 + threadIdx.x;
    if (e >= E_TOT) return;
    int src, dst;
    if (e < N_EDGES) { src = ei[e]; dst = ei[N_EDGES + e]; }
    else             { src = dst = e - N_EDGES; }
    int pos = atomicAdd(&cursor[dst], 1);
    csr[pos] = src;
}

// ---------------------------------------------------------------- fused attention
// One wave per dst; plain-sum softmax (scores bounded, shift-invariant).
__global__ __launch_bounds__(256) void attn_k(const float* __restrict__ xl,
                                              const float* __restrict__ xr,
                                              const int* __restrict__ rowptr,
                                              const int* __restrict__ csr,
                                              const float* __restrict__ att,
                                              const float* __restrict__ bias,
                                              float* __restrict__ out) {
    const int wid = threadIdx.x >> 6, lane = threadIdx.x & 63;
    const int dst = blockIdx.x * 4 + wid;
    if (dst >= N_NODES) return;
    const int pair = lane >> 5, s = lane & 31;
    const float4 xrv = *(const float4*)(xr + (size_t)dst * HC + s * 4);
    const float4 av  = *(const float4*)(att + s * 4);
    float l = 0.f;
    float4 acc = make_float4(0.f, 0.f, 0.f, 0.f);
    const int start = rowptr[dst], end = rowptr[dst + 1];

    for (int kb = start; kb < end; kb += 64) {
        int nk = min(64, end - kb);
        int sv = (kb + lane < end) ? csr[kb + lane] : 0;
        int j = 0;
        for (; j + 4 <= nk; j += 4) {
            int srcA = __shfl(sv, j + pair, 64);
            int srcB = __shfl(sv, j + 2 + pair, 64);
            float4 xa = *(const float4*)(xl + (size_t)srcA * HC + s * 4);
            float4 xb = *(const float4*)(xl + (size_t)srcB * HC + s * 4);
            {
                float t0 = xa.x + xrv.x; t0 = t0 > 0.f ? t0 : NEG_SLOPE * t0;
                float t1 = xa.y + xrv.y; t1 = t1 > 0.f ? t1 : NEG_SLOPE * t1;
                float t2 = xa.z + xrv.z; t2 = t2 > 0.f ? t2 : NEG_SLOPE * t2;
                float t3 = xa.w + xrv.w; t3 = t3 > 0.f ? t3 : NEG_SLOPE * t3;
                float part = av.x * t0 + av.y * t1 + av.z * t2 + av.w * t3;
                part += __shfl_xor(part, 1, 8);
                part += __shfl_xor(part, 2, 8);
                part += __shfl_xor(part, 4, 8);
                float p = __expf(part);
                l += p;
                acc.x += p * xa.x; acc.y += p * xa.y;
                acc.z += p * xa.z; acc.w += p * xa.w;
            }
            {
                float t0 = xb.x + xrv.x; t0 = t0 > 0.f ? t0 : NEG_SLOPE * t0;
                float t1 = xb.y + xrv.y; t1 = t1 > 0.f ? t1 : NEG_SLOPE * t1;
                float t2 = xb.z + xrv.z; t2 = t2 > 0.f ? t2 : NEG_SLOPE * t2;
                float t3 = xb.w + xrv.w; t3 = t3 > 0.f ? t3 : NEG_SLOPE * t3;
                float part = av.x * t0 + av.y * t1 + av.z * t2 + av.w * t3;
                part += __shfl_xor(part, 1, 8);
                part += __shfl_xor(part, 2, 8);
                part += __shfl_xor(part, 4, 8);
                float p = __expf(part);
                l += p;
                acc.x += p * xb.x; acc.y += p * xb.y;
                acc.z += p * xb.z; acc.w += p * xb.w;
            }
        }
        for (; j < nk; j += 2) {
            int idx = j + pair;
            bool valid = idx < nk;
            int src = __shfl(sv, valid ? idx : 0, 64);
            float4 xa = *(const float4*)(xl + (size_t)src * HC + s * 4);
            float t0 = xa.x + xrv.x; t0 = t0 > 0.f ? t0 : NEG_SLOPE * t0;
            float t1 = xa.y + xrv.y; t1 = t1 > 0.f ? t1 : NEG_SLOPE * t1;
            float t2 = xa.z + xrv.z; t2 = t2 > 0.f ? t2 : NEG_SLOPE * t2;
            float t3 = xa.w + xrv.w; t3 = t3 > 0.f ? t3 : NEG_SLOPE * t3;
            float part = av.x * t0 + av.y * t1 + av.z * t2 + av.w * t3;
            part += __shfl_xor(part, 1, 8);
            part += __shfl_xor(part, 2, 8);
            part += __shfl_xor(part, 4, 8);
            float p = valid ? __expf(part) : 0.f;
            l += p;
            acc.x += p * xa.x; acc.y += p * xa.y;
            acc.z += p * xa.z; acc.w += p * xa.w;
        }
    }
    l     += __shfl_xor(l, 32, 64);
    acc.x += __shfl_xor(acc.x, 32, 64);
    acc.y += __shfl_xor(acc.y, 32, 64);
    acc.z += __shfl_xor(acc.z, 32, 64);
    acc.w += __shfl_xor(acc.w, 32, 64);
    if (pair == 0) {
        float inv = 1.0f / l;
        float4 bv = *(const float4*)(bias + s * 4);
        float4 o = make_float4(acc.x * inv + bv.x, acc.y * inv + bv.y,
                               acc.z * inv + bv.z, acc.w * inv + bv.w);
        *(float4*)(out + (size_t)dst * HC + s * 4) = o;
    }
}

// ---------------------------------------------------------------- per-feature sum/sumsq
__global__ __launch_bounds__(256) void stats_k(const float* __restrict__ out,
                                               float* __restrict__ gsum,
                                               float* __restrict__ gsumsq) {
    int f = threadIdx.x & 127;
    int half = threadIdx.x >> 7;
    float s = 0.f, s2 = 0.f;
    for (int r = blockIdx.x * 2 + half; r < N_NODES; r += gridDim.x * 2) {
        float v = out[(size_t)r * HC + f];
        s += v; s2 += v * v;
    }
    __shared__ float l1[256], l2[256];
    l1[threadIdx.x] = s; l2[threadIdx.x] = s2;
    __syncthreads();
    if (threadIdx.x < 128) {
        s  = l1[threadIdx.x] + l1[threadIdx.x + 128];
        s2 = l2[threadIdx.x] + l2[threadIdx.x + 128];
        atomicAdd(&gsum[f], s);
        atomicAdd(&gsumsq[f], s2);
    }
}

// ---------------------------------------------------------------- GraphNorm finalize (in place on d_out)
__global__ __launch_bounds__(256) void norm_k(float* __restrict__ out,
                                              const float* __restrict__ gsum,
                                              const float* __restrict__ gsumsq,
                                              const float* __restrict__ gw,
                                              const float* __restrict__ gb,
                                              const float* __restrict__ gms) {
    int f = threadIdx.x & 127;
    int half = threadIdx.x >> 7;
    const float invN = 1.0f / (float)N_NODES;
    float mean = gsum[f] * invN;
    float msq  = gsumsq[f] * invN;
    float g = gms[f];
    float var = msq - 2.f * g * mean * mean + g * g * mean * mean;
    float rstd = rsqrtf(var + GN_EPS);
    float a = gw[f] * rstd;
    float b = gb[f] - a * g * mean;
    for (int r = blockIdx.x * 2 + half; r < N_NODES; r += gridDim.x * 2) {
        size_t o = (size_t)r * HC + f;
        out[o] = a * out[o] + b;
    }
}

// ---------------------------------------------------------------- launch
extern "C" void kernel_launch(void* const* d_in, const int* in_sizes, int n_in,
                              void* d_out, int out_size, void* d_ws, size_t ws_size,
                              hipStream_t stream) {
    const float* x    = (const float*)d_in[0];
    const int*   ei   = (const int*)d_in[1];
    const float* Wl   = (const float*)d_in[2];
    const float* Wr   = (const float*)d_in[3];
    const float* att  = (const float*)d_in[4];
    const float* bias = (const float*)d_in[5];
    const float* gw   = (const float*)d_in[6];
    const float* gb   = (const float*)d_in[7];
    const float* gms  = (const float*)d_in[8];
    float* out = (float*)d_out;

    float* xl     = (float*)d_ws;
    float* xr     = xl + (size_t)N_NODES * HC;
    float* gsum   = xr + (size_t)N_NODES * HC;
    float* gsumsq = gsum + HC;
    int*   deg    = (int*)(gsumsq + HC);
    int*   rowptr = deg + N_NODES;
    int*   cursor = rowptr + (N_NODES + 1);
    int*   csr    = cursor + N_NODES;
    ushort* wtl   = (ushort*)(csr + E_TOT);
    ushort* wtr   = wtl + 16384;
    int*   bsum   = (int*)(wtr + 16384);
    int*   boff   = bsum + SCAN_B;

    hipLaunchKernelGGL(init_k, dim3((N_NODES + 255) / 256), dim3(256), 0, stream,
                       deg, gsum, gsumsq, Wl, Wr, wtl, wtr);
    hipLaunchKernelGGL(gemm_k, dim3((N_NODES + 63) / 64, 2), dim3(256), 0, stream,
                       x, wtl, wtr, xl, xr);
    hipLaunchKernelGGL(hist_k, dim3((E_TOT + 255) / 256), dim3(256), 0, stream,
                       ei, deg);
    hipLaunchKernelGGL(scan1_k, dim3(SCAN_B), dim3(256), 0, stream,
                       deg, rowptr, bsum);
    hipLaunchKernelGGL(scan2_k, dim3(1), dim3(256), 0, stream,
                       bsum, boff);
    hipLaunchKernelGGL(scan3_k, dim3(SCAN_B), dim3(256), 0, stream,
                       rowptr, boff, cursor);
    hipLaunchKernelGGL(fill_k, dim3((E_TOT + 255) / 256), dim3(256), 0, stream,
                       ei, cursor, csr);
    hipLaunchKernelGGL(attn_k, dim3((N_NODES + 3) / 4), dim3(256), 0, stream,
                       xl, xr, rowptr, csr, att, bias, out);
    hipLaunchKernelGGL(stats_k, dim3(256), dim3(256), 0, stream,
                       out, gsum, gsumsq);
    hipLaunchKernelGGL(norm_k, dim3(512), dim3(256), 0, stream,
                       out, gsum, gsumsq, gw, gb, gms);
}